// Round 2
// baseline (893.534 us; speedup 1.0000x reference)
//
#include <hip/hip_runtime.h>

// Correlation cost volume: B=4, C=256, H=W=192, MAX_DISP=4 -> 81 displacements.
// out[b, dy*9+dx, y, x] = (1/C) * sum_c F[b,c,y,x] * Spad[b,c,y+dy-4,x+dx-4]
//
// R2: (a) F read directly from global into registers (9x redundant across the
//     block's waves but L1-resident) -> -25% LDS reads, no F LDS buffers.
//     (b) C split 4-ways across blocks: grid 2304 = 9.00 blocks/CU (was 2.25,
//     33% imbalance). Partials combined with global atomicAdd into memset-
//     zeroed output. S staging stays register-pipelined + double-buffered LDS.

#define MAXD 4
#define WINW 9
#define NDISP 81

constexpr int B_ = 4, C_ = 256, H_ = 192, W_ = 192;
constexpr int TH = 4;                    // output rows per block
constexpr int TW = 64;                   // output cols per block
constexpr int CSPLIT = 4;                // C-split factor (blocks per tile)
constexpr int CPB = C_ / CSPLIT;         // 64 channels per block
constexpr int CC = 4;                    // channels staged per chunk
constexpr int NCHUNK = CPB / CC;         // 16
constexpr int SROWS = TH + 2 * MAXD;     // 12
constexpr int SCOLS = TW + 2 * MAXD;     // 72
constexpr int S_STRIDE = 72;
constexpr int S_CH = SROWS * S_STRIDE;   // 864 floats per staged channel
constexpr int SBUF = CC * S_CH;          // 3456 floats per half
constexpr int NTHREADS = 576;            // 9 waves: wave id == dy
constexpr int NS4 = CC * SROWS * (SCOLS / 4);   // 864 float4 per chunk (S)

__global__ __launch_bounds__(NTHREADS)
void corr_kernel(const float* __restrict__ F, const float* __restrict__ S,
                 float* __restrict__ O) {
    __shared__ __align__(16) float ldsS[2 * SBUF];   // 27 KB (S only)

    const int tid  = threadIdx.x;
    const int y0   = blockIdx.x * TH;
    const int x0   = blockIdx.y * TW;
    const int zb   = blockIdx.z;
    const int b    = zb >> 2;            // batch
    const int cq   = zb & 3;             // C-split quarter
    const int dy   = tid >> 6;           // wave index = dy in [0,9)
    const int lane = tid & 63;
    const int xg   = lane & 15;          // x-group of 4 pixels
    const int yth  = lane >> 4;          // row within tile, [0,4)

    const long planeHW   = (long)H_ * W_;          // 36864
    const long chunkStep = (long)CC * planeHW;
    const float* Fb = F + ((long)b * C_ + cq * CPB) * planeHW;
    const float* Sb = S + ((long)b * C_ + cq * CPB) * planeHW;

    // ---- F: direct per-thread global pointer (own 4 px, always in-bounds) ----
    const float* fp = Fb + (long)(y0 + yth) * W_ + (x0 + 4 * xg);

    // ---- chunk-invariant S staging decomposition (hoisted) ----
    // slot 0: i = tid (< 864 always -> every thread active)
    const int  s0cc  = tid / (SROWS * (SCOLS / 4));            // /216
    const int  s0rem = tid - s0cc * (SROWS * (SCOLS / 4));
    const int  s0r   = s0rem / (SCOLS / 4);                    // /18
    const int  s0cg  = s0rem - s0r * (SCOLS / 4);
    const int  s0ys  = y0 - MAXD + s0r;
    const int  s0xs  = x0 - MAXD + 4 * s0cg;
    const bool s0In  = ((unsigned)s0ys < (unsigned)H_) &&
                       ((unsigned)s0xs <= (unsigned)(W_ - 4));
    const int  s0Lds = s0cc * S_CH + s0r * S_STRIDE + 4 * s0cg;
    const float* s0Ptr0 = Sb + (long)s0cc * planeHW + (long)s0ys * W_ + s0xs;

    // slot 1: i = tid + 576, active for tid < 288
    const int  i1    = tid + NTHREADS;
    const bool s1Act = (i1 < NS4);
    const int  s1cc  = i1 / (SROWS * (SCOLS / 4));
    const int  s1rem = i1 - s1cc * (SROWS * (SCOLS / 4));
    const int  s1r   = s1rem / (SCOLS / 4);
    const int  s1cg  = s1rem - s1r * (SCOLS / 4);
    const int  s1ys  = y0 - MAXD + s1r;
    const int  s1xs  = x0 - MAXD + 4 * s1cg;
    const bool s1In  = s1Act && ((unsigned)s1ys < (unsigned)H_) &&
                       ((unsigned)s1xs <= (unsigned)(W_ - 4));
    const int  s1Lds = s1cc * S_CH + s1r * S_STRIDE + 4 * s1cg;
    const float* s1Ptr0 = Sb + (long)s1cc * planeHW + (long)s1ys * W_ + s1xs;

    // ---- zero the OOB halo slots ONCE (both halves) ----
    const float4 z4 = make_float4(0.f, 0.f, 0.f, 0.f);
    if (!s0In) {
        *(float4*)(ldsS + s0Lds) = z4;
        *(float4*)(ldsS + SBUF + s0Lds) = z4;
    }
    if (s1Act && !s1In) {
        *(float4*)(ldsS + s1Lds) = z4;
        *(float4*)(ldsS + SBUF + s1Lds) = z4;
    }

    // ---- S pipeline: register prefetch + double-buffered LDS ----
    float4 ps0, ps1;
    const float* s0Next = s0Ptr0;
    const float* s1Next = s1Ptr0;

    auto loadS = [&]() {
        if (s0In) ps0 = *(const float4*)s0Next;
        if (s1In) ps1 = *(const float4*)s1Next;
        s0Next += chunkStep;
        s1Next += chunkStep;
    };
    auto writeS = [&](int half) {
        float* wS = ldsS + half * SBUF;
        if (s0In) *(float4*)(wS + s0Lds) = ps0;
        if (s1In) *(float4*)(wS + s1Lds) = ps1;
    };

    // ---- accumulators ----
    float acc[WINW][4];
    #pragma unroll
    for (int dx = 0; dx < WINW; ++dx)
        #pragma unroll
        for (int j = 0; j < 4; ++j) acc[dx][j] = 0.f;

    // ---- pipelined main loop: 1 barrier per chunk ----
    loadS();             // chunk 0 S -> regs
    writeS(0);           // chunk 0 -> LDS half 0
    loadS();             // chunk 1 S -> regs
    __syncthreads();

    const float* bS0 = ldsS + (yth + dy) * S_STRIDE + 4 * xg;

    for (int k = 0; k < NCHUNK; ++k) {
        // F for this chunk: 4 independent global loads (L1-hot after 1st wave)
        float4 fr[CC];
        #pragma unroll
        for (int cc = 0; cc < CC; ++cc)
            fr[cc] = *(const float4*)(fp + (long)cc * planeHW);
        fp += chunkStep;

        const int cur = k & 1;
        if (k + 1 < NCHUNK) {
            writeS(cur ^ 1);                 // chunk k+1 regs -> other half
            if (k + 2 < NCHUNK) loadS();     // issue chunk k+2 loads
        }

        // compute chunk k from LDS half cur
        const float* bS = bS0 + cur * SBUF;
        #pragma unroll
        for (int cc = 0; cc < CC; ++cc) {
            const float4 f  = fr[cc];
            const float4 w0 = *(const float4*)(bS + cc * S_CH);
            const float4 w1 = *(const float4*)(bS + cc * S_CH + 4);
            const float4 w2 = *(const float4*)(bS + cc * S_CH + 8);
            const float w[12] = {w0.x, w0.y, w0.z, w0.w,
                                 w1.x, w1.y, w1.z, w1.w,
                                 w2.x, w2.y, w2.z, w2.w};
            #pragma unroll
            for (int dx = 0; dx < WINW; ++dx) {
                acc[dx][0] += f.x * w[dx];
                acc[dx][1] += f.y * w[dx + 1];
                acc[dx][2] += f.z * w[dx + 2];
                acc[dx][3] += f.w * w[dx + 3];
            }
        }

        if (k + 1 < NCHUNK) __syncthreads();
    }

    // ---- epilogue: atomic combine of the 4 C-split partials ----
    const float scale = 1.0f / (float)C_;
    #pragma unroll
    for (int dx = 0; dx < WINW; ++dx) {
        const int d = dy * WINW + dx;
        float* dst = O + ((long)(b * NDISP + d) * H_ + (y0 + yth)) * W_ + x0 + 4 * xg;
        atomicAdd(dst + 0, acc[dx][0] * scale);
        atomicAdd(dst + 1, acc[dx][1] * scale);
        atomicAdd(dst + 2, acc[dx][2] * scale);
        atomicAdd(dst + 3, acc[dx][3] * scale);
    }
}

extern "C" void kernel_launch(void* const* d_in, const int* in_sizes, int n_in,
                              void* d_out, int out_size, void* d_ws, size_t ws_size,
                              hipStream_t stream) {
    const float* F = (const float*)d_in[0];
    const float* S = (const float*)d_in[1];
    float* O = (float*)d_out;
    hipMemsetAsync(d_out, 0, (size_t)out_size, stream);
    dim3 grid(H_ / TH, W_ / TW, B_ * CSPLIT);   // 48 x 3 x 16 = 2304 blocks
    dim3 block(NTHREADS);
    corr_kernel<<<grid, block, 0, stream>>>(F, S, O);
}

// Round 3
// 384.456 us; speedup vs baseline: 2.3242x; 2.3242x over previous
//
#include <hip/hip_runtime.h>

// Correlation cost volume: B=4, C=256, H=W=192, MAX_DISP=4 -> 81 displacements.
// out[b, dy*9+dx, y, x] = (1/C) * sum_c F[b,c,y,x] * Spad[b,c,y+dy-4,x+dx-4]
//
// R3: dy-split load balancing, NO atomics (R2 post-mortem: 48M atomicAdds ->
//     16x write amplification, 700us). Block = 3 waves handling dy in
//     {d0..d0+2}; grid = 48x3x12 = 1728 blocks = 6.75/CU (was 2.25 -> 33%
//     convoy). S tile 6 rows x 72, double-buffered (13.8 KB). F read directly
//     from global: same pixels for all 3 waves of a block -> L1 hits.

#define MAXD 4
#define WINW 9
#define NDISP 81

constexpr int B_ = 4, C_ = 256, H_ = 192, W_ = 192;
constexpr int TH = 4;                    // output rows per block
constexpr int TW = 64;                   // output cols per block
constexpr int DYS = 3;                   // dy values per block
constexpr int NDY = WINW / DYS;          // 3 dy groups
constexpr int CC = 4;                    // channels staged per chunk
constexpr int NCHUNK = C_ / CC;          // 64
constexpr int SROWS = TH + DYS - 1;      // 6 staged S rows
constexpr int SCOLS = TW + 2 * MAXD;     // 72
constexpr int S_STRIDE = 72;
constexpr int S_CH = SROWS * S_STRIDE;   // 432 floats per staged channel
constexpr int SBUF = CC * S_CH;          // 1728 floats per half
constexpr int NTHREADS = 64 * DYS;       // 192 threads = 3 waves
constexpr int NS4 = CC * SROWS * (SCOLS / 4);   // 432 float4 per chunk
constexpr int Q_CH = SROWS * (SCOLS / 4);       // 108 float4 per channel

__global__ __launch_bounds__(NTHREADS)
void corr_kernel(const float* __restrict__ F, const float* __restrict__ S,
                 float* __restrict__ O) {
    __shared__ __align__(16) float ldsS[2 * SBUF];   // 13.8 KB

    const int tid  = threadIdx.x;
    const int y0   = blockIdx.x * TH;
    const int x0   = blockIdx.y * TW;
    const int zb   = blockIdx.z;
    const int b    = zb / NDY;           // batch
    const int d0   = (zb % NDY) * DYS;   // first dy of this block
    const int widx = tid >> 6;           // wave index: dy = d0 + widx
    const int lane = tid & 63;
    const int xg   = lane & 15;          // x-group of 4 pixels
    const int yth  = lane >> 4;          // row within tile, [0,4)

    const long planeHW   = (long)H_ * W_;          // 36864
    const long chunkStep = (long)CC * planeHW;
    const float* Fb = F + (long)b * C_ * planeHW;
    const float* Sb = S + (long)b * C_ * planeHW;

    // ---- F: direct per-thread global pointer (same px for all 3 waves) ----
    const float* fp = Fb + (long)(y0 + yth) * W_ + (x0 + 4 * xg);

    // ---- chunk-invariant S staging decomposition (3 slots / thread) ----
    const int ybase = y0 + d0 - MAXD;    // first staged S row

    // slot 0: i = tid (always active)
    const int  s0cc  = tid / Q_CH;
    const int  s0rem = tid - s0cc * Q_CH;
    const int  s0r   = s0rem / (SCOLS / 4);
    const int  s0cg  = s0rem - s0r * (SCOLS / 4);
    const int  s0ys  = ybase + s0r;
    const int  s0xs  = x0 - MAXD + 4 * s0cg;
    const bool s0In  = ((unsigned)s0ys < (unsigned)H_) &&
                       ((unsigned)s0xs <= (unsigned)(W_ - 4));
    const int  s0Lds = s0cc * S_CH + s0r * S_STRIDE + 4 * s0cg;
    const float* s0Ptr0 = Sb + (long)s0cc * planeHW + (long)s0ys * W_ + s0xs;

    // slot 1: i = tid + 192 (always active: i in [192,384) < 432)
    const int  i1    = tid + NTHREADS;
    const int  s1cc  = i1 / Q_CH;
    const int  s1rem = i1 - s1cc * Q_CH;
    const int  s1r   = s1rem / (SCOLS / 4);
    const int  s1cg  = s1rem - s1r * (SCOLS / 4);
    const int  s1ys  = ybase + s1r;
    const int  s1xs  = x0 - MAXD + 4 * s1cg;
    const bool s1In  = ((unsigned)s1ys < (unsigned)H_) &&
                       ((unsigned)s1xs <= (unsigned)(W_ - 4));
    const int  s1Lds = s1cc * S_CH + s1r * S_STRIDE + 4 * s1cg;
    const float* s1Ptr0 = Sb + (long)s1cc * planeHW + (long)s1ys * W_ + s1xs;

    // slot 2: i = tid + 384, active for tid < 48
    const int  i2    = tid + 2 * NTHREADS;
    const bool s2Act = (i2 < NS4);
    const int  s2cc  = i2 / Q_CH;
    const int  s2rem = i2 - s2cc * Q_CH;
    const int  s2r   = s2rem / (SCOLS / 4);
    const int  s2cg  = s2rem - s2r * (SCOLS / 4);
    const int  s2ys  = ybase + s2r;
    const int  s2xs  = x0 - MAXD + 4 * s2cg;
    const bool s2In  = s2Act && ((unsigned)s2ys < (unsigned)H_) &&
                       ((unsigned)s2xs <= (unsigned)(W_ - 4));
    const int  s2Lds = s2cc * S_CH + s2r * S_STRIDE + 4 * s2cg;
    const float* s2Ptr0 = Sb + (long)s2cc * planeHW + (long)s2ys * W_ + s2xs;

    // ---- zero the OOB halo slots ONCE (both halves) ----
    const float4 z4 = make_float4(0.f, 0.f, 0.f, 0.f);
    if (!s0In) {
        *(float4*)(ldsS + s0Lds) = z4;
        *(float4*)(ldsS + SBUF + s0Lds) = z4;
    }
    if (!s1In) {
        *(float4*)(ldsS + s1Lds) = z4;
        *(float4*)(ldsS + SBUF + s1Lds) = z4;
    }
    if (s2Act && !s2In) {
        *(float4*)(ldsS + s2Lds) = z4;
        *(float4*)(ldsS + SBUF + s2Lds) = z4;
    }

    // ---- S pipeline: register prefetch + double-buffered LDS ----
    float4 ps0, ps1, ps2;
    const float* s0Next = s0Ptr0;
    const float* s1Next = s1Ptr0;
    const float* s2Next = s2Ptr0;

    auto loadS = [&]() {
        if (s0In) ps0 = *(const float4*)s0Next;
        if (s1In) ps1 = *(const float4*)s1Next;
        if (s2In) ps2 = *(const float4*)s2Next;
        s0Next += chunkStep;
        s1Next += chunkStep;
        s2Next += chunkStep;
    };
    auto writeS = [&](int half) {
        float* wS = ldsS + half * SBUF;
        if (s0In) *(float4*)(wS + s0Lds) = ps0;
        if (s1In) *(float4*)(wS + s1Lds) = ps1;
        if (s2In) *(float4*)(wS + s2Lds) = ps2;
    };

    // ---- accumulators ----
    float acc[WINW][4];
    #pragma unroll
    for (int dx = 0; dx < WINW; ++dx)
        #pragma unroll
        for (int j = 0; j < 4; ++j) acc[dx][j] = 0.f;

    // ---- pipelined main loop: 1 barrier per chunk ----
    loadS();             // chunk 0 -> regs
    writeS(0);           // chunk 0 -> LDS half 0
    loadS();             // chunk 1 -> regs
    __syncthreads();

    // wave widx computes dy = d0 + widx -> staged row (yth + widx)
    const float* bS0 = ldsS + (yth + widx) * S_STRIDE + 4 * xg;

    for (int k = 0; k < NCHUNK; ++k) {
        // F for this chunk: 4 global loads (L1-hot: shared by all 3 waves)
        float4 fr[CC];
        #pragma unroll
        for (int cc = 0; cc < CC; ++cc)
            fr[cc] = *(const float4*)(fp + (long)cc * planeHW);
        fp += chunkStep;

        const int cur = k & 1;
        if (k + 1 < NCHUNK) {
            writeS(cur ^ 1);                 // chunk k+1 regs -> other half
            if (k + 2 < NCHUNK) loadS();     // issue chunk k+2 loads
        }

        // compute chunk k from LDS half cur
        const float* bS = bS0 + cur * SBUF;
        #pragma unroll
        for (int cc = 0; cc < CC; ++cc) {
            const float4 f  = fr[cc];
            const float4 w0 = *(const float4*)(bS + cc * S_CH);
            const float4 w1 = *(const float4*)(bS + cc * S_CH + 4);
            const float4 w2 = *(const float4*)(bS + cc * S_CH + 8);
            const float w[12] = {w0.x, w0.y, w0.z, w0.w,
                                 w1.x, w1.y, w1.z, w1.w,
                                 w2.x, w2.y, w2.z, w2.w};
            #pragma unroll
            for (int dx = 0; dx < WINW; ++dx) {
                acc[dx][0] += f.x * w[dx];
                acc[dx][1] += f.y * w[dx + 1];
                acc[dx][2] += f.z * w[dx + 2];
                acc[dx][3] += f.w * w[dx + 3];
            }
        }

        if (k + 1 < NCHUNK) __syncthreads();
    }

    // ---- epilogue: 9 coalesced float4 stores (disjoint ownership) ----
    const float scale = 1.0f / (float)C_;
    const int dy = d0 + widx;
    #pragma unroll
    for (int dx = 0; dx < WINW; ++dx) {
        float4 o;
        o.x = acc[dx][0] * scale;
        o.y = acc[dx][1] * scale;
        o.z = acc[dx][2] * scale;
        o.w = acc[dx][3] * scale;
        const int d = dy * WINW + dx;
        float* dst = O + ((long)(b * NDISP + d) * H_ + (y0 + yth)) * W_ + x0 + 4 * xg;
        *(float4*)dst = o;
    }
}

extern "C" void kernel_launch(void* const* d_in, const int* in_sizes, int n_in,
                              void* d_out, int out_size, void* d_ws, size_t ws_size,
                              hipStream_t stream) {
    const float* F = (const float*)d_in[0];
    const float* S = (const float*)d_in[1];
    float* O = (float*)d_out;
    dim3 grid(H_ / TH, W_ / TW, B_ * NDY);   // 48 x 3 x 12 = 1728 blocks
    dim3 block(NTHREADS);
    corr_kernel<<<grid, block, 0, stream>>>(F, S, O);
}